// Round 12
// baseline (930.753 us; speedup 1.0000x reference)
//
#include <hip/hip_runtime.h>
#include <cstdint>

using u16 = unsigned short;
using u32 = uint32_t;
using u64 = unsigned long long;

typedef __bf16 bf16x8 __attribute__((ext_vector_type(8)));
typedef float  f32x4  __attribute__((ext_vector_type(4)));
typedef u32    uvec4  __attribute__((ext_vector_type(4)));

typedef const __attribute__((address_space(1))) void GV;
typedef __attribute__((address_space(3))) void LV;

#define MFMA(a, b, c) __builtin_amdgcn_mfma_f32_16x16x32_bf16((a), (b), (c), 0, 0, 0)
#define SCOPE_AGT __HIP_MEMORY_SCOPE_AGENT

static __device__ __forceinline__ void gl_lds16(const u16* g, u16* l) {
  __builtin_amdgcn_global_load_lds((GV*)g, (LV*)l, 16, 0, 0);
}
static __device__ __forceinline__ void st_dev(u64* p, u64 v) {
  __hip_atomic_store(p, v, __ATOMIC_RELAXED, SCOPE_AGT);
}
// spin until two adjacent padded flag lines reach tag (all lanes poll same addr)
static __device__ __forceinline__ void wait_pair(const u32* base, u32 tag) {
  while (__hip_atomic_load(base, __ATOMIC_RELAXED, SCOPE_AGT) < tag)
    __builtin_amdgcn_s_sleep(2);
  while (__hip_atomic_load(base + 32, __ATOMIC_RELAXED, SCOPE_AGT) < tag)
    __builtin_amdgcn_s_sleep(2);
}

// ---------------- numeric helpers ----------------
static __device__ __forceinline__ u16 f2bf(float x) {
  u32 u = __float_as_uint(x);
  u32 r = (u + 0x7FFFu + ((u >> 16) & 1u)) >> 16;   // RNE
  return (u16)r;
}

static __device__ __forceinline__ u32 rotl32(u32 v, int s) {
  return (v << s) | (v >> (32 - s));
}

// JAX threefry2x32 (20 rounds)
static __device__ __forceinline__ void threefry2x32(u32 k0, u32 k1, u32 x0, u32 x1,
                                                    u32& o0, u32& o1) {
  u32 k2 = k0 ^ k1 ^ 0x1BD11BDAu;
  x0 += k0; x1 += k1;
  x0 += x1; x1 = rotl32(x1, 13); x1 ^= x0;
  x0 += x1; x1 = rotl32(x1, 15); x1 ^= x0;
  x0 += x1; x1 = rotl32(x1, 26); x1 ^= x0;
  x0 += x1; x1 = rotl32(x1, 6);  x1 ^= x0;
  x0 += k1; x1 += k2 + 1u;
  x0 += x1; x1 = rotl32(x1, 17); x1 ^= x0;
  x0 += x1; x1 = rotl32(x1, 29); x1 ^= x0;
  x0 += x1; x1 = rotl32(x1, 16); x1 ^= x0;
  x0 += x1; x1 = rotl32(x1, 24); x1 ^= x0;
  x0 += k2; x1 += k0 + 2u;
  x0 += x1; x1 = rotl32(x1, 13); x1 ^= x0;
  x0 += x1; x1 = rotl32(x1, 15); x1 ^= x0;
  x0 += x1; x1 = rotl32(x1, 26); x1 ^= x0;
  x0 += x1; x1 = rotl32(x1, 6);  x1 ^= x0;
  x0 += k0; x1 += k1 + 3u;
  x0 += x1; x1 = rotl32(x1, 17); x1 ^= x0;
  x0 += x1; x1 = rotl32(x1, 29); x1 ^= x0;
  x0 += x1; x1 = rotl32(x1, 16); x1 ^= x0;
  x0 += x1; x1 = rotl32(x1, 24); x1 ^= x0;
  x0 += k1; x1 += k2 + 4u;
  x0 += x1; x1 = rotl32(x1, 13); x1 ^= x0;
  x0 += x1; x1 = rotl32(x1, 15); x1 ^= x0;
  x0 += x1; x1 = rotl32(x1, 26); x1 ^= x0;
  x0 += x1; x1 = rotl32(x1, 6);  x1 ^= x0;
  x0 += k2; x1 += k0 + 5u;
  o0 = x0; o1 = x1;
}

// bits -> N(0,1) exactly like jax.random.normal(f32)
static __device__ __forceinline__ float bits_to_normal(u32 bits) {
  const float lo = __uint_as_float(0xBF7FFFFFu);
  float f = __uint_as_float((bits >> 9) | 0x3F800000u) - 1.0f;
  float x = fmaxf(lo, f * 2.0f + lo);
  float w = -logf((1.0f - x) * (1.0f + x));
  float p;
  if (w < 5.0f) {
    w -= 2.5f;
    p = 2.81022636e-08f;
    p = fmaf(p, w, 3.43273939e-07f);
    p = fmaf(p, w, -3.5233877e-06f);
    p = fmaf(p, w, -4.39150654e-06f);
    p = fmaf(p, w, 0.00021858087f);
    p = fmaf(p, w, -0.00125372503f);
    p = fmaf(p, w, -0.00417768164f);
    p = fmaf(p, w, 0.246640727f);
    p = fmaf(p, w, 1.50140941f);
  } else {
    w = sqrtf(w) - 3.0f;
    p = -0.000200214257f;
    p = fmaf(p, w, 0.000100950558f);
    p = fmaf(p, w, 0.00134934322f);
    p = fmaf(p, w, -0.00367342844f);
    p = fmaf(p, w, 0.00573950773f);
    p = fmaf(p, w, -0.0076224613f);
    p = fmaf(p, w, 0.00943887047f);
    p = fmaf(p, w, 1.00167406f);
    p = fmaf(p, w, 2.83297682f);
  }
  return 1.41421356f * p * x;
}

// ---------------- S1: fragment-pack weights from f32 (r7 layout) ----------------
__global__ __launch_bounds__(256) void s1_frag(
    const float* __restrict__ W1f, const float* __restrict__ W1g,
    const float* __restrict__ W2f, const float* __restrict__ W2g,
    u16* __restrict__ W1P, u16* __restrict__ W2P) {
  const int gid = blockIdx.x * 256 + threadIdx.x;
  const int f = gid >> 6, l = gid & 63;
  const int lr = l & 15, kg = l >> 4;
  u32 wbuf[4];
  if (f < 16384) {                       // W1P: (net*64+ct)*128 + q
    const int net = f >> 13, r = f & 8191, ct = r >> 7, q = r & 127;
    const float* __restrict__ src = net ? W1g : W1f;
    const int k = q * 32 + kg * 8, c = ct * 16 + lr;
    #pragma unroll
    for (int p = 0; p < 4; ++p) {
      u16 e0 = f2bf(src[(size_t)(k + 2 * p) * 1024 + c]);
      u16 e1 = f2bf(src[(size_t)(k + 2 * p + 1) * 1024 + c]);
      wbuf[p] = (u32)e0 | ((u32)e1 << 16);
    }
    *(uvec4*)(W1P + (size_t)f * 512 + l * 8) = *(uvec4*)wbuf;
  } else {                               // W2P: (net*256+ct16)*32 + q
    const int f2 = f - 16384;
    const int net = f2 >> 13, r = f2 & 8191, ct = r >> 5, q = r & 31;
    const float* __restrict__ src = net ? W2g : W2f;
    const int k = q * 32 + kg * 8, c = ct * 16 + lr;
    #pragma unroll
    for (int p = 0; p < 4; ++p) {
      u16 e0 = f2bf(src[(size_t)(k + 2 * p) * 4096 + c]);
      u16 e1 = f2bf(src[(size_t)(k + 2 * p + 1) * 4096 + c]);
      wbuf[p] = (u32)e0 | ((u32)e1 << 16);
    }
    *(uvec4*)(W2P + (size_t)f2 * 512 + l * 8) = *(uvec4*)wbuf;
  }
}

// ---------------- S2: t=0 output, APack[0] init, counters zero ----------------
__global__ __launch_bounds__(256) void s2_init(
    const float* __restrict__ A0, u16* __restrict__ APack,
    u32* __restrict__ ctr, float* __restrict__ out) {
  const int gid = blockIdx.x * 256 + threadIdx.x;   // 262144
  const int n = gid & 4095, b = gid >> 12;
  const float a0 = A0[gid];
  const float sig = (n % 65 == 0) ? 0.0f : 1.0f / (1.0f + expf(-a0));
  #pragma unroll
  for (int s = 0; s < 4; ++s)
    out[((size_t)(s * 64) * 64 + b) * 4096 + n] = sig;
  if (gid < 32768) {                     // APack[0]: [m 4][q 128] frags
    const int fr = gid >> 6, l = gid & 63;
    const int m = fr >> 7, q = fr & 127;
    const int row = m * 16 + (l & 15);
    const int k = q * 32 + (l >> 4) * 8;
    u32 wbuf[4];
    #pragma unroll
    for (int p = 0; p < 4; ++p) {
      u16 e0 = f2bf(A0[(size_t)row * 4096 + k + 2 * p]);
      u16 e1 = f2bf(A0[(size_t)row * 4096 + k + 2 * p + 1]);
      wbuf[p] = (u32)e0 | ((u32)e1 << 16);
    }
    *(uvec4*)(APack + (size_t)fr * 512 + l * 8) = *(uvec4*)wbuf;
  }
  if (gid < 2048) ctr[gid] = 0;          // flag lines; re-zero every launch
}

// ---------------- fused 63-step SDE: W1 VGPR, W2 LDS, producer-group flags ----------------
// flag lines (padded 128B): A-arrive: ctr[(mp*8+g)*32], B-arrive: ctr[(16+mp*8+g)*32]
__global__ __launch_bounds__(512) void sde_fused(
    const float* __restrict__ A0, const float* __restrict__ tarr,
    const u16* __restrict__ W1P, const u16* __restrict__ W2P,
    const float* __restrict__ b1f, const float* __restrict__ b1g,
    const float* __restrict__ W1fv, const float* __restrict__ W1gv,
    const float* __restrict__ b2f, const float* __restrict__ b2g,
    u16* __restrict__ APack, u16* __restrict__ HPack,
    u32* __restrict__ ctr, float* __restrict__ out) {
  extern __shared__ __align__(16) char smraw[];
  u16* w2l = (u16*)smraw;                                    // 128 KB W2 slice
  char* exraw = smraw + 131072;
  f32x4 (*paex)[64]     = (f32x4 (*)[64])exraw;              // 8 KB
  u16 (*patile)[16][16] = (u16 (*)[16][16])(exraw + 8192);   // 1 KB
  f32x4 (*pbex)[64][2]  = (f32x4 (*)[64][2])exraw;           // 16 KB (aliases paex)
  u16 (*pbtile)[16][32] = (u16 (*)[16][32])(exraw + 16384);  // 2 KB
  uint2* dwk = (uint2*)(exraw + 18432);                      // 504 B

  const int bid = blockIdx.x, tix = threadIdx.x;
  const int wid = tix >> 6, lane = tix & 63;
  const int lr = lane & 15, lq = lane >> 4;
  const int mp = bid >> 7;
  const int ctF = bid & 127;
  const int netA = ctF >> 6, ctA = ctF & 63;
  const int mA = wid & 1, ksA = wid >> 1;
  const int mGA = mp * 2 + mA;
  const int ct32 = bid & 127;
  const int ksB = wid >> 2, netB = (wid >> 1) & 1, mB = wid & 1;
  const int mGB = mp * 2 + mB;
  const int eM = wid & 1, eCf = (wid >> 1) & 1, eRh = wid >> 2;
  const int nc = ct32 * 32 + eCf * 16 + lr;
  const int g = ctF >> 4;
  u32* arrA = ctr + (mp * 8 + g) * 32;
  u32* arrB = ctr + (16 + mp * 8 + g) * 32;
  const u32* waitA = ctr + (16 + mp * 8 + ksA * 2) * 32;        // phase A waits on B-arrivals
  const u32* waitB = ctr + (mp * 8 + netB * 4 + ksB * 2) * 32;  // phase B waits on A-arrivals

  // ---- prologue: W2 slice -> LDS (f = net*64 + c*32 + ks*16 + d)
  #pragma unroll
  for (int i = 0; i < 16; ++i) {
    const int f = wid * 16 + i;
    const int nf = f >> 6, cf = (f >> 5) & 1, ksf = (f >> 4) & 1, df = f & 15;
    const u16* src = W2P
        + ((size_t)((nf * 256 + ct32 * 2 + cf) * 32 + ksf * 16 + df)) * 512 + lane * 8;
    gl_lds16(src, w2l + (size_t)f * 512);
  }
  if (tix < 63) {                        // dW step keys
    u32 y0, y1;
    threefry2x32(0u, 42u, 0u, (u32)tix, y0, y1);
    dwk[tix] = make_uint2(y0, y1);
  }
  // persistent W1 column slice: 32 frags
  bf16x8 wv[32];
  {
    const u16* pw = W1P + ((size_t)((netA * 64 + ctA) * 128 + ksA * 32)) * 512 + lane * 8;
    #pragma unroll
    for (int d = 0; d < 32; ++d) wv[d] = *(const bf16x8*)(pw + (size_t)d * 512);
  }
  // A-state in registers + hoisted epilogue constants
  float Ast[2];
  #pragma unroll
  for (int ri = 0; ri < 2; ++ri) {
    const int row = mp * 32 + eM * 16 + lq * 4 + eRh * 2 + ri;
    Ast[ri] = A0[(size_t)row * 4096 + nc];
  }
  const int nclA = ctA * 16 + lr;
  const float bAc = (netA ? b1g : b1f)[nclA];
  const float wAc = ((netA ? W1gv : W1fv) + (size_t)4096 * 1024)[nclA];
  const float bfv = b2f[nc], bgv = b2g[nc];
  const bool diag0 = (nc % 65 == 0);
  asm volatile("s_waitcnt vmcnt(0)" ::: "memory");
  __syncthreads();

  const float dt = tarr[1] - tarr[0];
  const float sdt = sqrtf(dt);

  for (int step = 0; step < 63; ++step) {
    // ===== phase A: HPack[step] = frag(tanh(A @ W1 + b1 + t*w1last)) =====
    {
      wait_pair(waitA, 16u * (u32)step);
      const u16* pa = APack + (size_t)step * 262144
                    + ((size_t)(mGA * 128 + ksA * 32)) * 512 + lane * 8;
      bf16x8 av[16];
      #pragma unroll
      for (int d = 0; d < 16; ++d) av[d] = *(const bf16x8*)(pa + (size_t)d * 512);
      f32x4 acc0 = {0.f, 0.f, 0.f, 0.f}, acc1 = acc0;
      #pragma unroll
      for (int j = 0; j < 32; ++j) {
        const int s = j & 15;
        if (j & 1) acc1 = MFMA(av[s], wv[j], acc1);
        else       acc0 = MFMA(av[s], wv[j], acc0);
        if (j + 16 < 32) av[s] = *(const bf16x8*)(pa + (size_t)(j + 16) * 512);
      }
      paex[wid][lane] = acc0 + acc1;
      __syncthreads();
      {
        const int gM = wid & 1, gR = wid >> 1;
        const f32x4 s0 = paex[gM][lane];
        const f32x4 s1 = paex[2 + gM][lane];
        const f32x4 s2 = paex[4 + gM][lane];
        const f32x4 s3 = paex[6 + gM][lane];
        const float ch = s0[gR] + s1[gR] + s2[gR] + s3[gR];
        const float cc = bAc + tarr[step] * wAc;
        patile[gM][lq * 4 + gR][lr] = f2bf(tanhf(ch + cc));
      }
      __syncthreads();
      if (wid < 2 && lane < 32) {
        const int mm = wid;
        const int row = lane & 15, kp = lane >> 4;
        const u16* src = &patile[mm][row][kp * 8];
        const u64 lo = *(const u64*)src;
        const u64 hi = *(const u64*)(src + 4);
        const int k8 = (ctA & 1) * 2 + kp;
        u16* dst = HPack + (size_t)step * 131072
                 + ((size_t)((netA * 4 + mp * 2 + mm) * 32 + (ctA >> 1))) * 512
                 + (k8 * 16 + row) * 8;
        st_dev((u64*)dst, lo);
        st_dev((u64*)dst + 1, hi);
      }
      asm volatile("s_waitcnt vmcnt(0)" ::: "memory");
      __syncthreads();
      if (tix == 0)
        __hip_atomic_fetch_add(arrA, 1u, __ATOMIC_RELAXED, SCOPE_AGT);
    }

    // ===== phase B: C = H @ W2 (f,g) -> SDE update =====
    {
      wait_pair(waitB, 16u * (u32)(step + 1));
      const u16* ph = HPack + (size_t)step * 131072
                    + ((size_t)((netB * 4 + mGB) * 32 + ksB * 16)) * 512 + lane * 8;
      bf16x8 hv[8];
      #pragma unroll
      for (int d = 0; d < 8; ++d) hv[d] = *(const bf16x8*)(ph + (size_t)d * 512);
      const u16* wl0 = w2l + (size_t)(netB * 64 + ksB * 16) * 512 + lane * 8;
      const u16* wl1 = wl0 + (size_t)32 * 512;
      f32x4 a0 = {0.f, 0.f, 0.f, 0.f}, a1 = a0;
      #pragma unroll
      for (int j = 0; j < 16; ++j) {
        const int s = j & 7;
        const bf16x8 w0 = *(const bf16x8*)(wl0 + (size_t)j * 512);
        const bf16x8 w1 = *(const bf16x8*)(wl1 + (size_t)j * 512);
        a0 = MFMA(hv[s], w0, a0);
        a1 = MFMA(hv[s], w1, a1);
        if (j + 8 < 16) hv[s] = *(const bf16x8*)(ph + (size_t)(j + 8) * 512);
      }
      pbex[wid][lane][0] = a0;
      pbex[wid][lane][1] = a1;
      __syncthreads();
      float sg[2];
      {
        const f32x4 CF = pbex[eM][lane][eCf] + pbex[4 + eM][lane][eCf];
        const f32x4 CG = pbex[2 + eM][lane][eCf] + pbex[6 + eM][lane][eCf];
        const uint2 key = dwk[step];
        #pragma unroll
        for (int ri = 0; ri < 2; ++ri) {
          const int r = eRh * 2 + ri;
          const int row = mp * 32 + eM * 16 + lq * 4 + r;
          const float drift = CF[r] + bfv;
          const float graw = CG[r] + bgv;
          const float diff = fmaxf(graw, 0.0f) + log1pf(expf(-fabsf(graw)));
          u32 y0, y1;
          threefry2x32(key.x, key.y, 0u, (u32)(row * 4096 + nc), y0, y1);
          const float dw = bits_to_normal(y0 ^ y1) * sdt;
          const float an = Ast[ri] + drift * dt + diff * dw;
          Ast[ri] = an;
          pbtile[eM][lq * 4 + r][eCf * 16 + lr] = f2bf(an);
          sg[ri] = diag0 ? 0.0f : 1.0f / (1.0f + expf(-an));
        }
      }
      __syncthreads();
      if (wid < 2) {
        const int mm = wid;
        const int row = lane & 15, kq = lane >> 4;
        const u16* src = &pbtile[mm][row][kq * 8];
        const u64 lo = *(const u64*)src;
        const u64 hi = *(const u64*)(src + 4);
        u16* dst = APack + (size_t)(step + 1) * 262144
                 + ((size_t)((mp * 2 + mm) * 128 + ct32)) * 512 + lane * 8;
        st_dev((u64*)dst, lo);
        st_dev((u64*)dst + 1, hi);
      }
      asm volatile("s_waitcnt vmcnt(0)" ::: "memory");
      __syncthreads();
      if (tix == 0)
        __hip_atomic_fetch_add(arrB, 1u, __ATOMIC_RELAXED, SCOPE_AGT);
      // deferred output stores: drain overlaps next-step wait/loads
      #pragma unroll
      for (int ri = 0; ri < 2; ++ri) {
        const int row = mp * 32 + eM * 16 + lq * 4 + eRh * 2 + ri;
        #pragma unroll
        for (int s = 0; s < 4; ++s)
          __builtin_nontemporal_store(
              sg[ri], &out[((size_t)(s * 64 + step + 1) * 64 + row) * 4096 + nc]);
      }
    }
  }
}

// ---------------- launch ----------------
extern "C" void kernel_launch(void* const* d_in, const int* in_sizes, int n_in,
                              void* d_out, int out_size, void* d_ws, size_t ws_size,
                              hipStream_t stream) {
  const float* A0 = (const float*)d_in[0];
  const float* tarr = (const float*)d_in[1];
  const float* W1f = (const float*)d_in[2];
  const float* b1f = (const float*)d_in[3];
  const float* W2f = (const float*)d_in[4];
  const float* b2f = (const float*)d_in[5];
  const float* W1g = (const float*)d_in[6];
  const float* b1g = (const float*)d_in[7];
  const float* W2g = (const float*)d_in[8];
  const float* b2g = (const float*)d_in[9];
  float* outp = (float*)d_out;
  char* ws = (char*)d_ws;
  const size_t MB = 1024 * 1024;
  u16* W1P   = (u16*)(ws + 0 * MB);        // 16 MB frag-packed
  u16* W2P   = (u16*)(ws + 16 * MB);       // 16 MB
  u16* APack = (u16*)(ws + 32 * MB);       // 64 step-buffers x 512 KB = 32 MB
  u16* HPack = (u16*)(ws + 64 * MB);       // 63 step-buffers x 256 KB ~ 16 MB
  u32* ctr   = (u32*)(ws + 80 * MB);       // padded flag lines (8 KB)

  s1_frag<<<dim3(8192), 256, 0, stream>>>(W1f, W1g, W2f, W2g, W1P, W2P);
  s2_init<<<dim3(1024), 256, 0, stream>>>(A0, APack, ctr, outp);

  void* kargs[] = {
    (void*)&A0, (void*)&tarr,
    (void*)&W1P, (void*)&W2P,
    (void*)&b1f, (void*)&b1g, (void*)&W1f, (void*)&W1g,
    (void*)&b2f, (void*)&b2g,
    (void*)&APack, (void*)&HPack, (void*)&ctr, (void*)&outp
  };
  hipLaunchCooperativeKernel((const void*)sde_fused, dim3(256), dim3(512),
                             kargs, 150016, stream);
}

// Round 13
// 798.633 us; speedup vs baseline: 1.1654x; 1.1654x over previous
//
#include <hip/hip_runtime.h>
#include <cstdint>

using u16 = unsigned short;
using u32 = uint32_t;
using u64 = unsigned long long;

typedef __bf16 bf16x8 __attribute__((ext_vector_type(8)));
typedef float  f32x4  __attribute__((ext_vector_type(4)));
typedef u32    uvec4  __attribute__((ext_vector_type(4)));

typedef const __attribute__((address_space(1))) void GV;
typedef __attribute__((address_space(3))) void LV;

#define MFMA(a, b, c) __builtin_amdgcn_mfma_f32_16x16x32_bf16((a), (b), (c), 0, 0, 0)
#define SCOPE_AGT __HIP_MEMORY_SCOPE_AGENT

static __device__ __forceinline__ void gl_lds16(const u16* g, u16* l) {
  __builtin_amdgcn_global_load_lds((GV*)g, (LV*)l, 16, 0, 0);
}
static __device__ __forceinline__ void st_dev(u64* p, u64 v) {
  __hip_atomic_store(p, v, __ATOMIC_RELAXED, SCOPE_AGT);
}
// aggregator: wave 0 polls 128 per-block flag lines (lane-parallel), then sets GO
static __device__ __forceinline__ void aggregate(const u32* p0, const u32* p1,
                                                 u32* go, u32 tag) {
  for (;;) {
    u32 a = __hip_atomic_load(p0, __ATOMIC_RELAXED, SCOPE_AGT);
    u32 b = __hip_atomic_load(p1, __ATOMIC_RELAXED, SCOPE_AGT);
    if (__all(a >= tag) && __all(b >= tag)) break;
    __builtin_amdgcn_s_sleep(1);
  }
  __hip_atomic_store(go, tag, __ATOMIC_RELAXED, SCOPE_AGT);
}
// single-thread GO poll, then release block
static __device__ __forceinline__ void wait_go(const u32* go, u32 tag) {
  if (threadIdx.x == 0)
    while (__hip_atomic_load(go, __ATOMIC_RELAXED, SCOPE_AGT) < tag)
      __builtin_amdgcn_s_sleep(2);
  __syncthreads();
}

// ---------------- numeric helpers ----------------
static __device__ __forceinline__ u16 f2bf(float x) {
  u32 u = __float_as_uint(x);
  u32 r = (u + 0x7FFFu + ((u >> 16) & 1u)) >> 16;   // RNE
  return (u16)r;
}

static __device__ __forceinline__ u32 rotl32(u32 v, int s) {
  return (v << s) | (v >> (32 - s));
}

// JAX threefry2x32 (20 rounds)
static __device__ __forceinline__ void threefry2x32(u32 k0, u32 k1, u32 x0, u32 x1,
                                                    u32& o0, u32& o1) {
  u32 k2 = k0 ^ k1 ^ 0x1BD11BDAu;
  x0 += k0; x1 += k1;
  x0 += x1; x1 = rotl32(x1, 13); x1 ^= x0;
  x0 += x1; x1 = rotl32(x1, 15); x1 ^= x0;
  x0 += x1; x1 = rotl32(x1, 26); x1 ^= x0;
  x0 += x1; x1 = rotl32(x1, 6);  x1 ^= x0;
  x0 += k1; x1 += k2 + 1u;
  x0 += x1; x1 = rotl32(x1, 17); x1 ^= x0;
  x0 += x1; x1 = rotl32(x1, 29); x1 ^= x0;
  x0 += x1; x1 = rotl32(x1, 16); x1 ^= x0;
  x0 += x1; x1 = rotl32(x1, 24); x1 ^= x0;
  x0 += k2; x1 += k0 + 2u;
  x0 += x1; x1 = rotl32(x1, 13); x1 ^= x0;
  x0 += x1; x1 = rotl32(x1, 15); x1 ^= x0;
  x0 += x1; x1 = rotl32(x1, 26); x1 ^= x0;
  x0 += x1; x1 = rotl32(x1, 6);  x1 ^= x0;
  x0 += k0; x1 += k1 + 3u;
  x0 += x1; x1 = rotl32(x1, 17); x1 ^= x0;
  x0 += x1; x1 = rotl32(x1, 29); x1 ^= x0;
  x0 += x1; x1 = rotl32(x1, 16); x1 ^= x0;
  x0 += x1; x1 = rotl32(x1, 24); x1 ^= x0;
  x0 += k1; x1 += k2 + 4u;
  x0 += x1; x1 = rotl32(x1, 13); x1 ^= x0;
  x0 += x1; x1 = rotl32(x1, 15); x1 ^= x0;
  x0 += x1; x1 = rotl32(x1, 26); x1 ^= x0;
  x0 += x1; x1 = rotl32(x1, 6);  x1 ^= x0;
  x0 += k2; x1 += k0 + 5u;
  o0 = x0; o1 = x1;
}

// bits -> N(0,1) exactly like jax.random.normal(f32)
static __device__ __forceinline__ float bits_to_normal(u32 bits) {
  const float lo = __uint_as_float(0xBF7FFFFFu);
  float f = __uint_as_float((bits >> 9) | 0x3F800000u) - 1.0f;
  float x = fmaxf(lo, f * 2.0f + lo);
  float w = -logf((1.0f - x) * (1.0f + x));
  float p;
  if (w < 5.0f) {
    w -= 2.5f;
    p = 2.81022636e-08f;
    p = fmaf(p, w, 3.43273939e-07f);
    p = fmaf(p, w, -3.5233877e-06f);
    p = fmaf(p, w, -4.39150654e-06f);
    p = fmaf(p, w, 0.00021858087f);
    p = fmaf(p, w, -0.00125372503f);
    p = fmaf(p, w, -0.00417768164f);
    p = fmaf(p, w, 0.246640727f);
    p = fmaf(p, w, 1.50140941f);
  } else {
    w = sqrtf(w) - 3.0f;
    p = -0.000200214257f;
    p = fmaf(p, w, 0.000100950558f);
    p = fmaf(p, w, 0.00134934322f);
    p = fmaf(p, w, -0.00367342844f);
    p = fmaf(p, w, 0.00573950773f);
    p = fmaf(p, w, -0.0076224613f);
    p = fmaf(p, w, 0.00943887047f);
    p = fmaf(p, w, 1.00167406f);
    p = fmaf(p, w, 2.83297682f);
  }
  return 1.41421356f * p * x;
}

// ---------------- S1: fragment-pack weights from f32 (r7 layout) ----------------
__global__ __launch_bounds__(256) void s1_frag(
    const float* __restrict__ W1f, const float* __restrict__ W1g,
    const float* __restrict__ W2f, const float* __restrict__ W2g,
    u16* __restrict__ W1P, u16* __restrict__ W2P) {
  const int gid = blockIdx.x * 256 + threadIdx.x;
  const int f = gid >> 6, l = gid & 63;
  const int lr = l & 15, kg = l >> 4;
  u32 wbuf[4];
  if (f < 16384) {                       // W1P: (net*64+ct)*128 + q
    const int net = f >> 13, r = f & 8191, ct = r >> 7, q = r & 127;
    const float* __restrict__ src = net ? W1g : W1f;
    const int k = q * 32 + kg * 8, c = ct * 16 + lr;
    #pragma unroll
    for (int p = 0; p < 4; ++p) {
      u16 e0 = f2bf(src[(size_t)(k + 2 * p) * 1024 + c]);
      u16 e1 = f2bf(src[(size_t)(k + 2 * p + 1) * 1024 + c]);
      wbuf[p] = (u32)e0 | ((u32)e1 << 16);
    }
    *(uvec4*)(W1P + (size_t)f * 512 + l * 8) = *(uvec4*)wbuf;
  } else {                               // W2P: (net*256+ct16)*32 + q
    const int f2 = f - 16384;
    const int net = f2 >> 13, r = f2 & 8191, ct = r >> 5, q = r & 31;
    const float* __restrict__ src = net ? W2g : W2f;
    const int k = q * 32 + kg * 8, c = ct * 16 + lr;
    #pragma unroll
    for (int p = 0; p < 4; ++p) {
      u16 e0 = f2bf(src[(size_t)(k + 2 * p) * 4096 + c]);
      u16 e1 = f2bf(src[(size_t)(k + 2 * p + 1) * 4096 + c]);
      wbuf[p] = (u32)e0 | ((u32)e1 << 16);
    }
    *(uvec4*)(W2P + (size_t)f2 * 512 + l * 8) = *(uvec4*)wbuf;
  }
}

// ---------------- S2: t=0 output, APack[0] init, flag lines zero ----------------
__global__ __launch_bounds__(256) void s2_init(
    const float* __restrict__ A0, u16* __restrict__ APack,
    u32* __restrict__ ctr, float* __restrict__ out) {
  const int gid = blockIdx.x * 256 + threadIdx.x;   // 262144
  const int n = gid & 4095, b = gid >> 12;
  const float a0 = A0[gid];
  const float sig = (n % 65 == 0) ? 0.0f : 1.0f / (1.0f + expf(-a0));
  #pragma unroll
  for (int s = 0; s < 4; ++s)
    out[((size_t)(s * 64) * 64 + b) * 4096 + n] = sig;
  if (gid < 32768) {                     // APack[0]: [m 4][q 128] frags
    const int fr = gid >> 6, l = gid & 63;
    const int m = fr >> 7, q = fr & 127;
    const int row = m * 16 + (l & 15);
    const int k = q * 32 + (l >> 4) * 8;
    u32 wbuf[4];
    #pragma unroll
    for (int p = 0; p < 4; ++p) {
      u16 e0 = f2bf(A0[(size_t)row * 4096 + k + 2 * p]);
      u16 e1 = f2bf(A0[(size_t)row * 4096 + k + 2 * p + 1]);
      wbuf[p] = (u32)e0 | ((u32)e1 << 16);
    }
    *(uvec4*)(APack + (size_t)fr * 512 + l * 8) = *(uvec4*)wbuf;
  }
  if (gid < 16640) ctr[gid] = 0;         // flag/GO lines; re-zero every launch
}

// ---------------- fused 63-step SDE: W1 VGPR, W2 LDS, flag-array barrier ----------------
// ctr lines (128B each): flagsA = bid, flagsB = 256+bid, goA = 512+mp, goB = 514+mp
__global__ __launch_bounds__(512, 2) void sde_fused(
    const float* __restrict__ A0, const float* __restrict__ tarr,
    const u16* __restrict__ W1P, const u16* __restrict__ W2P,
    const float* __restrict__ b1f, const float* __restrict__ b1g,
    const float* __restrict__ W1fv, const float* __restrict__ W1gv,
    const float* __restrict__ b2f, const float* __restrict__ b2g,
    u16* __restrict__ APack, u16* __restrict__ HPack,
    u32* __restrict__ ctr, float* __restrict__ out) {
  extern __shared__ __align__(16) char smraw[];
  u16* w2l = (u16*)smraw;                                    // 128 KB W2 slice
  char* exraw = smraw + 131072;
  f32x4 (*paex)[64]     = (f32x4 (*)[64])exraw;              // 8 KB
  u16 (*patile)[16][16] = (u16 (*)[16][16])(exraw + 8192);   // 1 KB
  f32x4 (*pbex)[64][2]  = (f32x4 (*)[64][2])exraw;           // 16 KB (aliases paex)
  u16 (*pbtile)[16][32] = (u16 (*)[16][32])(exraw + 16384);  // 2 KB
  uint2* dwk = (uint2*)(exraw + 18432);                      // 504 B

  const int bid = blockIdx.x, tix = threadIdx.x;
  const int wid = tix >> 6, lane = tix & 63;
  const int lr = lane & 15, lq = lane >> 4;
  const int mp = bid >> 7;
  const int ctF = bid & 127;
  const int netA = ctF >> 6, ctA = ctF & 63;
  const int mA = wid & 1, ksA = wid >> 1;
  const int mGA = mp * 2 + mA;
  const int ct32 = bid & 127;
  const int ksB = wid >> 2, netB = (wid >> 1) & 1, mB = wid & 1;
  const int mGB = mp * 2 + mB;
  const int eM = wid & 1, eCf = (wid >> 1) & 1, eRh = wid >> 2;
  const int nc = ct32 * 32 + eCf * 16 + lr;

  // barrier plumbing
  u32* myFlagA = ctr + (size_t)bid * 32;
  u32* myFlagB = ctr + (size_t)(256 + bid) * 32;
  const u32* aggA0 = ctr + (size_t)(mp * 128 + lane) * 32;
  const u32* aggA1 = ctr + (size_t)(mp * 128 + 64 + lane) * 32;
  const u32* aggB0 = ctr + (size_t)(256 + mp * 128 + lane) * 32;
  const u32* aggB1 = ctr + (size_t)(256 + mp * 128 + 64 + lane) * 32;
  u32* goA = ctr + (size_t)(512 + mp) * 32;
  u32* goB = ctr + (size_t)(514 + mp) * 32;
  const bool isagg = ((bid & 127) == 0);

  // ---- prologue: W2 slice -> LDS (f = net*64 + c*32 + ks*16 + d)
  #pragma unroll
  for (int i = 0; i < 16; ++i) {
    const int f = wid * 16 + i;
    const int nf = f >> 6, cf = (f >> 5) & 1, ksf = (f >> 4) & 1, df = f & 15;
    const u16* src = W2P
        + ((size_t)((nf * 256 + ct32 * 2 + cf) * 32 + ksf * 16 + df)) * 512 + lane * 8;
    gl_lds16(src, w2l + (size_t)f * 512);
  }
  if (tix < 63) {                        // dW step keys
    u32 y0, y1;
    threefry2x32(0u, 42u, 0u, (u32)tix, y0, y1);
    dwk[tix] = make_uint2(y0, y1);
  }
  // persistent W1 column slice: 32 frags = 128 VGPR (enabled by launch_bounds(512,2))
  bf16x8 wv[32];
  {
    const u16* pw = W1P + ((size_t)((netA * 64 + ctA) * 128 + ksA * 32)) * 512 + lane * 8;
    #pragma unroll
    for (int d = 0; d < 32; ++d) wv[d] = *(const bf16x8*)(pw + (size_t)d * 512);
  }
  // A-state in registers + hoisted epilogue constants
  float Ast[2];
  #pragma unroll
  for (int ri = 0; ri < 2; ++ri) {
    const int row = mp * 32 + eM * 16 + lq * 4 + eRh * 2 + ri;
    Ast[ri] = A0[(size_t)row * 4096 + nc];
  }
  const int nclA = ctA * 16 + lr;
  const float bAc = (netA ? b1g : b1f)[nclA];
  const float wAc = ((netA ? W1gv : W1fv) + (size_t)4096 * 1024)[nclA];
  const float bfv = b2f[nc], bgv = b2g[nc];
  const bool diag0 = (nc % 65 == 0);
  asm volatile("s_waitcnt vmcnt(0)" ::: "memory");
  __syncthreads();

  const float dt = tarr[1] - tarr[0];
  const float sdt = sqrtf(dt);

  for (int step = 0; step < 63; ++step) {
    const u32 tag = (u32)step + 1u;
    // ===== phase A: HPack[step] = frag(tanh(A @ W1 + b1 + t*w1last)) =====
    {
      wait_go(goB, (u32)step);           // APack[step] ready (trivial at step 0)
      const u16* pa = APack + (size_t)step * 262144
                    + ((size_t)(mGA * 128 + ksA * 32)) * 512 + lane * 8;
      bf16x8 av[16];
      #pragma unroll
      for (int d = 0; d < 16; ++d) av[d] = *(const bf16x8*)(pa + (size_t)d * 512);
      f32x4 acc0 = {0.f, 0.f, 0.f, 0.f}, acc1 = acc0;
      #pragma unroll
      for (int j = 0; j < 32; ++j) {
        const int s = j & 15;
        if (j & 1) acc1 = MFMA(av[s], wv[j], acc1);
        else       acc0 = MFMA(av[s], wv[j], acc0);
        if (j + 16 < 32) av[s] = *(const bf16x8*)(pa + (size_t)(j + 16) * 512);
      }
      paex[wid][lane] = acc0 + acc1;
      __syncthreads();
      {
        const int gM = wid & 1, gR = wid >> 1;
        const f32x4 s0 = paex[gM][lane];
        const f32x4 s1 = paex[2 + gM][lane];
        const f32x4 s2 = paex[4 + gM][lane];
        const f32x4 s3 = paex[6 + gM][lane];
        const float ch = s0[gR] + s1[gR] + s2[gR] + s3[gR];
        const float cc = bAc + tarr[step] * wAc;
        patile[gM][lq * 4 + gR][lr] = f2bf(tanhf(ch + cc));
      }
      __syncthreads();
      if (wid < 2 && lane < 32) {
        const int mm = wid;
        const int row = lane & 15, kp = lane >> 4;
        const u16* src = &patile[mm][row][kp * 8];
        const u64 lo = *(const u64*)src;
        const u64 hi = *(const u64*)(src + 4);
        const int k8 = (ctA & 1) * 2 + kp;
        u16* dst = HPack + (size_t)step * 131072
                 + ((size_t)((netA * 4 + mp * 2 + mm) * 32 + (ctA >> 1))) * 512
                 + (k8 * 16 + row) * 8;
        st_dev((u64*)dst, lo);
        st_dev((u64*)dst + 1, hi);
      }
      asm volatile("s_waitcnt vmcnt(0)" ::: "memory");
      __syncthreads();
      if (tix == 0)
        __hip_atomic_store(myFlagA, tag, __ATOMIC_RELAXED, SCOPE_AGT);
      if (isagg && wid == 0) aggregate(aggA0, aggA1, goA, tag);
    }

    // ===== phase B: C = H @ W2 (f,g) -> SDE update =====
    {
      wait_go(goA, tag);                 // HPack[step] ready
      const u16* ph = HPack + (size_t)step * 131072
                    + ((size_t)((netB * 4 + mGB) * 32 + ksB * 16)) * 512 + lane * 8;
      bf16x8 hv[8];
      #pragma unroll
      for (int d = 0; d < 8; ++d) hv[d] = *(const bf16x8*)(ph + (size_t)d * 512);
      const u16* wl0 = w2l + (size_t)(netB * 64 + ksB * 16) * 512 + lane * 8;
      const u16* wl1 = wl0 + (size_t)32 * 512;
      f32x4 a0 = {0.f, 0.f, 0.f, 0.f}, a1 = a0;
      #pragma unroll
      for (int j = 0; j < 16; ++j) {
        const int s = j & 7;
        const bf16x8 w0 = *(const bf16x8*)(wl0 + (size_t)j * 512);
        const bf16x8 w1 = *(const bf16x8*)(wl1 + (size_t)j * 512);
        a0 = MFMA(hv[s], w0, a0);
        a1 = MFMA(hv[s], w1, a1);
        if (j + 8 < 16) hv[s] = *(const bf16x8*)(ph + (size_t)(j + 8) * 512);
      }
      pbex[wid][lane][0] = a0;
      pbex[wid][lane][1] = a1;
      __syncthreads();
      float sg[2];
      {
        const f32x4 CF = pbex[eM][lane][eCf] + pbex[4 + eM][lane][eCf];
        const f32x4 CG = pbex[2 + eM][lane][eCf] + pbex[6 + eM][lane][eCf];
        const uint2 key = dwk[step];
        #pragma unroll
        for (int ri = 0; ri < 2; ++ri) {
          const int r = eRh * 2 + ri;
          const int row = mp * 32 + eM * 16 + lq * 4 + r;
          const float drift = CF[r] + bfv;
          const float graw = CG[r] + bgv;
          const float diff = fmaxf(graw, 0.0f) + log1pf(expf(-fabsf(graw)));
          u32 y0, y1;
          threefry2x32(key.x, key.y, 0u, (u32)(row * 4096 + nc), y0, y1);
          const float dw = bits_to_normal(y0 ^ y1) * sdt;
          const float an = Ast[ri] + drift * dt + diff * dw;
          Ast[ri] = an;
          pbtile[eM][lq * 4 + r][eCf * 16 + lr] = f2bf(an);
          sg[ri] = diag0 ? 0.0f : 1.0f / (1.0f + expf(-an));
        }
      }
      __syncthreads();
      if (wid < 2) {
        const int mm = wid;
        const int row = lane & 15, kq = lane >> 4;
        const u16* src = &pbtile[mm][row][kq * 8];
        const u64 lo = *(const u64*)src;
        const u64 hi = *(const u64*)(src + 4);
        u16* dst = APack + (size_t)(step + 1) * 262144
                 + ((size_t)((mp * 2 + mm) * 128 + ct32)) * 512 + lane * 8;
        st_dev((u64*)dst, lo);
        st_dev((u64*)dst + 1, hi);
      }
      asm volatile("s_waitcnt vmcnt(0)" ::: "memory");
      __syncthreads();
      if (step < 62 && tix == 0)
        __hip_atomic_store(myFlagB, tag, __ATOMIC_RELAXED, SCOPE_AGT);
      // deferred output stores: drain overlaps aggregation / next-step wait
      #pragma unroll
      for (int ri = 0; ri < 2; ++ri) {
        const int row = mp * 32 + eM * 16 + lq * 4 + eRh * 2 + ri;
        #pragma unroll
        for (int s = 0; s < 4; ++s)
          __builtin_nontemporal_store(
              sg[ri], &out[((size_t)(s * 64 + step + 1) * 64 + row) * 4096 + nc]);
      }
      if (step < 62 && isagg && wid == 0) aggregate(aggB0, aggB1, goB, tag);
    }
  }
}

// ---------------- launch ----------------
extern "C" void kernel_launch(void* const* d_in, const int* in_sizes, int n_in,
                              void* d_out, int out_size, void* d_ws, size_t ws_size,
                              hipStream_t stream) {
  const float* A0 = (const float*)d_in[0];
  const float* tarr = (const float*)d_in[1];
  const float* W1f = (const float*)d_in[2];
  const float* b1f = (const float*)d_in[3];
  const float* W2f = (const float*)d_in[4];
  const float* b2f = (const float*)d_in[5];
  const float* W1g = (const float*)d_in[6];
  const float* b1g = (const float*)d_in[7];
  const float* W2g = (const float*)d_in[8];
  const float* b2g = (const float*)d_in[9];
  float* outp = (float*)d_out;
  char* ws = (char*)d_ws;
  const size_t MB = 1024 * 1024;
  u16* W1P   = (u16*)(ws + 0 * MB);        // 16 MB frag-packed
  u16* W2P   = (u16*)(ws + 16 * MB);       // 16 MB
  u16* APack = (u16*)(ws + 32 * MB);       // 64 step-buffers x 512 KB = 32 MB
  u16* HPack = (u16*)(ws + 64 * MB);       // 63 step-buffers x 256 KB ~ 16 MB
  u32* ctr   = (u32*)(ws + 80 * MB);       // 516 padded flag/GO lines (~66 KB)

  s1_frag<<<dim3(8192), 256, 0, stream>>>(W1f, W1g, W2f, W2g, W1P, W2P);
  s2_init<<<dim3(1024), 256, 0, stream>>>(A0, APack, ctr, outp);

  void* kargs[] = {
    (void*)&A0, (void*)&tarr,
    (void*)&W1P, (void*)&W2P,
    (void*)&b1f, (void*)&b1g, (void*)&W1f, (void*)&W1g,
    (void*)&b2f, (void*)&b2g,
    (void*)&APack, (void*)&HPack, (void*)&ctr, (void*)&outp
  };
  hipLaunchCooperativeKernel((const void*)sde_fused, dim3(256), dim3(512),
                             kargs, 150016, stream);
}

// Round 14
// 724.402 us; speedup vs baseline: 1.2849x; 1.1025x over previous
//
#include <hip/hip_runtime.h>
#include <cstdint>

using u16 = unsigned short;
using u32 = uint32_t;
using u64 = unsigned long long;

typedef __bf16 bf16x8 __attribute__((ext_vector_type(8)));
typedef float  f32x4  __attribute__((ext_vector_type(4)));
typedef u32    uvec4  __attribute__((ext_vector_type(4)));

typedef const __attribute__((address_space(1))) void GV;
typedef __attribute__((address_space(3))) void LV;

#define MFMA(a, b, c) __builtin_amdgcn_mfma_f32_16x16x32_bf16((a), (b), (c), 0, 0, 0)
#define SCOPE_AGT __HIP_MEMORY_SCOPE_AGENT

static __device__ __forceinline__ void gl_lds16(const u16* g, u16* l) {
  __builtin_amdgcn_global_load_lds((GV*)g, (LV*)l, 16, 0, 0);
}
static __device__ __forceinline__ void st_dev(u64* p, u64 v) {
  __hip_atomic_store(p, v, __ATOMIC_RELAXED, SCOPE_AGT);
}
// per-wave wait: poll 32 producer tag lines (padded 128B) until all >= tag
static __device__ __forceinline__ void wait_tags(const u32* ctr, int base, u32 tag) {
  const int lane = threadIdx.x & 63;
  const u32* p = ctr + (size_t)(base + (lane & 31)) * 32;
  u32 v = __hip_atomic_load(p, __ATOMIC_RELAXED, SCOPE_AGT);
  while (!__all(v >= tag)) {
    __builtin_amdgcn_s_sleep(4);
    v = __hip_atomic_load(p, __ATOMIC_RELAXED, SCOPE_AGT);
  }
  asm volatile("" ::: "memory");   // keep data loads below the wait
}

// ---------------- numeric helpers ----------------
static __device__ __forceinline__ u16 f2bf(float x) {
  u32 u = __float_as_uint(x);
  u32 r = (u + 0x7FFFu + ((u >> 16) & 1u)) >> 16;   // RNE
  return (u16)r;
}

static __device__ __forceinline__ u32 rotl32(u32 v, int s) {
  return (v << s) | (v >> (32 - s));
}

// JAX threefry2x32 (20 rounds)
static __device__ __forceinline__ void threefry2x32(u32 k0, u32 k1, u32 x0, u32 x1,
                                                    u32& o0, u32& o1) {
  u32 k2 = k0 ^ k1 ^ 0x1BD11BDAu;
  x0 += k0; x1 += k1;
  x0 += x1; x1 = rotl32(x1, 13); x1 ^= x0;
  x0 += x1; x1 = rotl32(x1, 15); x1 ^= x0;
  x0 += x1; x1 = rotl32(x1, 26); x1 ^= x0;
  x0 += x1; x1 = rotl32(x1, 6);  x1 ^= x0;
  x0 += k1; x1 += k2 + 1u;
  x0 += x1; x1 = rotl32(x1, 17); x1 ^= x0;
  x0 += x1; x1 = rotl32(x1, 29); x1 ^= x0;
  x0 += x1; x1 = rotl32(x1, 16); x1 ^= x0;
  x0 += x1; x1 = rotl32(x1, 24); x1 ^= x0;
  x0 += k2; x1 += k0 + 2u;
  x0 += x1; x1 = rotl32(x1, 13); x1 ^= x0;
  x0 += x1; x1 = rotl32(x1, 15); x1 ^= x0;
  x0 += x1; x1 = rotl32(x1, 26); x1 ^= x0;
  x0 += x1; x1 = rotl32(x1, 6);  x1 ^= x0;
  x0 += k0; x1 += k1 + 3u;
  x0 += x1; x1 = rotl32(x1, 17); x1 ^= x0;
  x0 += x1; x1 = rotl32(x1, 29); x1 ^= x0;
  x0 += x1; x1 = rotl32(x1, 16); x1 ^= x0;
  x0 += x1; x1 = rotl32(x1, 24); x1 ^= x0;
  x0 += k1; x1 += k2 + 4u;
  x0 += x1; x1 = rotl32(x1, 13); x1 ^= x0;
  x0 += x1; x1 = rotl32(x1, 15); x1 ^= x0;
  x0 += x1; x1 = rotl32(x1, 26); x1 ^= x0;
  x0 += x1; x1 = rotl32(x1, 6);  x1 ^= x0;
  x0 += k2; x1 += k0 + 5u;
  o0 = x0; o1 = x1;
}

// bits -> N(0,1) exactly like jax.random.normal(f32)
static __device__ __forceinline__ float bits_to_normal(u32 bits) {
  const float lo = __uint_as_float(0xBF7FFFFFu);
  float f = __uint_as_float((bits >> 9) | 0x3F800000u) - 1.0f;
  float x = fmaxf(lo, f * 2.0f + lo);
  float w = -logf((1.0f - x) * (1.0f + x));
  float p;
  if (w < 5.0f) {
    w -= 2.5f;
    p = 2.81022636e-08f;
    p = fmaf(p, w, 3.43273939e-07f);
    p = fmaf(p, w, -3.5233877e-06f);
    p = fmaf(p, w, -4.39150654e-06f);
    p = fmaf(p, w, 0.00021858087f);
    p = fmaf(p, w, -0.00125372503f);
    p = fmaf(p, w, -0.00417768164f);
    p = fmaf(p, w, 0.246640727f);
    p = fmaf(p, w, 1.50140941f);
  } else {
    w = sqrtf(w) - 3.0f;
    p = -0.000200214257f;
    p = fmaf(p, w, 0.000100950558f);
    p = fmaf(p, w, 0.00134934322f);
    p = fmaf(p, w, -0.00367342844f);
    p = fmaf(p, w, 0.00573950773f);
    p = fmaf(p, w, -0.0076224613f);
    p = fmaf(p, w, 0.00943887047f);
    p = fmaf(p, w, 1.00167406f);
    p = fmaf(p, w, 2.83297682f);
  }
  return 1.41421356f * p * x;
}

// ---------------- S1: fragment-pack weights from f32 (r7 layout) ----------------
__global__ __launch_bounds__(256) void s1_frag(
    const float* __restrict__ W1f, const float* __restrict__ W1g,
    const float* __restrict__ W2f, const float* __restrict__ W2g,
    u16* __restrict__ W1P, u16* __restrict__ W2P) {
  const int gid = blockIdx.x * 256 + threadIdx.x;
  const int f = gid >> 6, l = gid & 63;
  const int lr = l & 15, kg = l >> 4;
  u32 wbuf[4];
  if (f < 16384) {                       // W1P: (net*64+ct)*128 + q
    const int net = f >> 13, r = f & 8191, ct = r >> 7, q = r & 127;
    const float* __restrict__ src = net ? W1g : W1f;
    const int k = q * 32 + kg * 8, c = ct * 16 + lr;
    #pragma unroll
    for (int p = 0; p < 4; ++p) {
      u16 e0 = f2bf(src[(size_t)(k + 2 * p) * 1024 + c]);
      u16 e1 = f2bf(src[(size_t)(k + 2 * p + 1) * 1024 + c]);
      wbuf[p] = (u32)e0 | ((u32)e1 << 16);
    }
    *(uvec4*)(W1P + (size_t)f * 512 + l * 8) = *(uvec4*)wbuf;
  } else {                               // W2P: (net*256+ct16)*32 + q
    const int f2 = f - 16384;
    const int net = f2 >> 13, r = f2 & 8191, ct = r >> 5, q = r & 31;
    const float* __restrict__ src = net ? W2g : W2f;
    const int k = q * 32 + kg * 8, c = ct * 16 + lr;
    #pragma unroll
    for (int p = 0; p < 4; ++p) {
      u16 e0 = f2bf(src[(size_t)(k + 2 * p) * 4096 + c]);
      u16 e1 = f2bf(src[(size_t)(k + 2 * p + 1) * 4096 + c]);
      wbuf[p] = (u32)e0 | ((u32)e1 << 16);
    }
    *(uvec4*)(W2P + (size_t)f2 * 512 + l * 8) = *(uvec4*)wbuf;
  }
}

// ---------------- S2: t=0 output, APack[0] init, tag lines zero ----------------
__global__ __launch_bounds__(256) void s2_init(
    const float* __restrict__ A0, u16* __restrict__ APack,
    u32* __restrict__ ctr, float* __restrict__ out) {
  const int gid = blockIdx.x * 256 + threadIdx.x;   // 262144
  const int n = gid & 4095, b = gid >> 12;
  const float a0 = A0[gid];
  const float sig = (n % 65 == 0) ? 0.0f : 1.0f / (1.0f + expf(-a0));
  #pragma unroll
  for (int s = 0; s < 4; ++s)
    out[((size_t)(s * 64) * 64 + b) * 4096 + n] = sig;
  if (gid < 32768) {                     // APack[0]: [m 4][q 128] frags
    const int fr = gid >> 6, l = gid & 63;
    const int m = fr >> 7, q = fr & 127;
    const int row = m * 16 + (l & 15);
    const int k = q * 32 + (l >> 4) * 8;
    u32 wbuf[4];
    #pragma unroll
    for (int p = 0; p < 4; ++p) {
      u16 e0 = f2bf(A0[(size_t)row * 4096 + k + 2 * p]);
      u16 e1 = f2bf(A0[(size_t)row * 4096 + k + 2 * p + 1]);
      wbuf[p] = (u32)e0 | ((u32)e1 << 16);
    }
    *(uvec4*)(APack + (size_t)fr * 512 + l * 8) = *(uvec4*)wbuf;
  }
  if (gid < 16640) ctr[gid] = 0;         // tag lines; re-zero every launch (replays)
}

// ---------------- fused 63-step SDE: W1 regs, W2 LDS, tag-array direct sync ----------------
// ctr lines (128B): tagA = bid (phase A done), tagB = 256+bid (phase B done)
__global__ __launch_bounds__(512, 2) void sde_fused(
    const float* __restrict__ A0, const float* __restrict__ tarr,
    const u16* __restrict__ W1P, const u16* __restrict__ W2P,
    const float* __restrict__ b1f, const float* __restrict__ b1g,
    const float* __restrict__ W1fv, const float* __restrict__ W1gv,
    const float* __restrict__ b2f, const float* __restrict__ b2g,
    u16* __restrict__ APack, u16* __restrict__ HPack,
    u32* __restrict__ ctr, float* __restrict__ out) {
  extern __shared__ __align__(16) char smraw[];
  u16* w2l = (u16*)smraw;                                    // 128 KB W2 slice
  char* exraw = smraw + 131072;
  f32x4 (*paex)[64]     = (f32x4 (*)[64])exraw;              // 8 KB
  u16 (*patile)[16][16] = (u16 (*)[16][16])(exraw + 8192);   // 1 KB
  f32x4 (*pbex)[64][2]  = (f32x4 (*)[64][2])exraw;           // 16 KB (aliases paex)
  u16 (*pbtile)[16][32] = (u16 (*)[16][32])(exraw + 16384);  // 2 KB
  uint2* dwk = (uint2*)(exraw + 18432);                      // 504 B

  const int bid = blockIdx.x, tix = threadIdx.x;
  const int wid = tix >> 6, lane = tix & 63;
  const int lr = lane & 15, lq = lane >> 4;
  const int mp = bid >> 7;
  const int ctF = bid & 127;
  const int netA = ctF >> 6, ctA = ctF & 63;
  const int mA = wid & 1, ksA = wid >> 1;
  const int mGA = mp * 2 + mA;
  const int ct32 = bid & 127;
  const int ksB = wid >> 2, netB = (wid >> 1) & 1, mB = wid & 1;
  const int mGB = mp * 2 + mB;
  const int eM = wid & 1, eCf = (wid >> 1) & 1, eRh = wid >> 2;
  const int nc = ct32 * 32 + eCf * 16 + lr;

  // tag plumbing
  u32* tagA = ctr + (size_t)bid * 32;
  u32* tagB = ctr + (size_t)(256 + bid) * 32;
  const int waitAbase = 256 + mp * 128 + ksA * 32;        // phase A needs these B-producers
  const int waitBbase = mp * 128 + netB * 64 + ksB * 32;  // phase B needs these A-producers

  // ---- prologue: W2 slice -> LDS (f = net*64 + c*32 + ks*16 + d)
  #pragma unroll
  for (int i = 0; i < 16; ++i) {
    const int f = wid * 16 + i;
    const int nf = f >> 6, cf = (f >> 5) & 1, ksf = (f >> 4) & 1, df = f & 15;
    const u16* src = W2P
        + ((size_t)((nf * 256 + ct32 * 2 + cf) * 32 + ksf * 16 + df)) * 512 + lane * 8;
    gl_lds16(src, w2l + (size_t)f * 512);
  }
  if (tix < 63) {                        // dW step keys
    u32 y0, y1;
    threefry2x32(0u, 42u, 0u, (u32)tix, y0, y1);
    dwk[tix] = make_uint2(y0, y1);
  }
  // persistent W1 column slice: 32 frags
  bf16x8 wv[32];
  {
    const u16* pw = W1P + ((size_t)((netA * 64 + ctA) * 128 + ksA * 32)) * 512 + lane * 8;
    #pragma unroll
    for (int d = 0; d < 32; ++d) wv[d] = *(const bf16x8*)(pw + (size_t)d * 512);
  }
  // A-state in registers + hoisted epilogue constants
  float Ast[2];
  #pragma unroll
  for (int ri = 0; ri < 2; ++ri) {
    const int row = mp * 32 + eM * 16 + lq * 4 + eRh * 2 + ri;
    Ast[ri] = A0[(size_t)row * 4096 + nc];
  }
  const int nclA = ctA * 16 + lr;
  const float bAc = (netA ? b1g : b1f)[nclA];
  const float wAc = ((netA ? W1gv : W1fv) + (size_t)4096 * 1024)[nclA];
  const float bfv = b2f[nc], bgv = b2g[nc];
  const bool diag0 = (nc % 65 == 0);
  asm volatile("s_waitcnt vmcnt(0)" ::: "memory");
  __syncthreads();

  const float dt = tarr[1] - tarr[0];
  const float sdt = sqrtf(dt);

  for (int step = 0; step < 63; ++step) {
    const u32 tag = (u32)step + 1u;
    // ===== phase A: HPack[step] = frag(tanh(A @ W1 + b1 + t*w1last)) =====
    {
      wait_tags(ctr, waitAbase, (u32)step);   // APack[step] producers done (trivial at 0)
      const u16* pa = APack + (size_t)step * 262144
                    + ((size_t)(mGA * 128 + ksA * 32)) * 512 + lane * 8;
      bf16x8 av[16];
      #pragma unroll
      for (int d = 0; d < 16; ++d) av[d] = *(const bf16x8*)(pa + (size_t)d * 512);
      f32x4 acc0 = {0.f, 0.f, 0.f, 0.f}, acc1 = acc0;
      #pragma unroll
      for (int j = 0; j < 32; ++j) {
        const int s = j & 15;
        if (j & 1) acc1 = MFMA(av[s], wv[j], acc1);
        else       acc0 = MFMA(av[s], wv[j], acc0);
        if (j + 16 < 32) av[s] = *(const bf16x8*)(pa + (size_t)(j + 16) * 512);
      }
      paex[wid][lane] = acc0 + acc1;
      __syncthreads();
      {
        const int gM = wid & 1, gR = wid >> 1;
        const f32x4 s0 = paex[gM][lane];
        const f32x4 s1 = paex[2 + gM][lane];
        const f32x4 s2 = paex[4 + gM][lane];
        const f32x4 s3 = paex[6 + gM][lane];
        const float ch = s0[gR] + s1[gR] + s2[gR] + s3[gR];
        const float cc = bAc + tarr[step] * wAc;
        patile[gM][lq * 4 + gR][lr] = f2bf(tanhf(ch + cc));
      }
      __syncthreads();
      if (wid < 2 && lane < 32) {
        const int mm = wid;
        const int row = lane & 15, kp = lane >> 4;
        const u16* src = &patile[mm][row][kp * 8];
        const u64 lo = *(const u64*)src;
        const u64 hi = *(const u64*)(src + 4);
        const int k8 = (ctA & 1) * 2 + kp;
        u16* dst = HPack + (size_t)step * 131072
                 + ((size_t)((netA * 4 + mp * 2 + mm) * 32 + (ctA >> 1))) * 512
                 + (k8 * 16 + row) * 8;
        st_dev((u64*)dst, lo);
        st_dev((u64*)dst + 1, hi);
      }
      asm volatile("s_waitcnt vmcnt(0)" ::: "memory");
      __syncthreads();
      if (tix == 0)
        __hip_atomic_store(tagA, tag, __ATOMIC_RELAXED, SCOPE_AGT);
    }

    // ===== phase B: C = H @ W2 (f,g) -> SDE update =====
    {
      wait_tags(ctr, waitBbase, tag);    // HPack[step] producers done
      const u16* ph = HPack + (size_t)step * 131072
                    + ((size_t)((netB * 4 + mGB) * 32 + ksB * 16)) * 512 + lane * 8;
      bf16x8 hv[16];
      #pragma unroll
      for (int d = 0; d < 16; ++d) hv[d] = *(const bf16x8*)(ph + (size_t)d * 512);
      const u16* wl0 = w2l + (size_t)(netB * 64 + ksB * 16) * 512 + lane * 8;
      const u16* wl1 = wl0 + (size_t)32 * 512;
      f32x4 a0 = {0.f, 0.f, 0.f, 0.f}, a1 = a0;
      #pragma unroll
      for (int j = 0; j < 16; ++j) {
        const bf16x8 w0 = *(const bf16x8*)(wl0 + (size_t)j * 512);
        const bf16x8 w1 = *(const bf16x8*)(wl1 + (size_t)j * 512);
        a0 = MFMA(hv[j], w0, a0);
        a1 = MFMA(hv[j], w1, a1);
      }
      pbex[wid][lane][0] = a0;
      pbex[wid][lane][1] = a1;
      __syncthreads();
      float sg[2];
      {
        const f32x4 CF = pbex[eM][lane][eCf] + pbex[4 + eM][lane][eCf];
        const f32x4 CG = pbex[2 + eM][lane][eCf] + pbex[6 + eM][lane][eCf];
        const uint2 key = dwk[step];
        #pragma unroll
        for (int ri = 0; ri < 2; ++ri) {
          const int r = eRh * 2 + ri;
          const int row = mp * 32 + eM * 16 + lq * 4 + r;
          const float drift = CF[r] + bfv;
          const float graw = CG[r] + bgv;
          const float diff = fmaxf(graw, 0.0f) + log1pf(expf(-fabsf(graw)));
          u32 y0, y1;
          threefry2x32(key.x, key.y, 0u, (u32)(row * 4096 + nc), y0, y1);
          const float dw = bits_to_normal(y0 ^ y1) * sdt;
          const float an = Ast[ri] + drift * dt + diff * dw;
          Ast[ri] = an;
          pbtile[eM][lq * 4 + r][eCf * 16 + lr] = f2bf(an);
          sg[ri] = diag0 ? 0.0f : 1.0f / (1.0f + expf(-an));
        }
      }
      __syncthreads();
      if (wid < 2) {
        const int mm = wid;
        const int row = lane & 15, kq = lane >> 4;
        const u16* src = &pbtile[mm][row][kq * 8];
        const u64 lo = *(const u64*)src;
        const u64 hi = *(const u64*)(src + 4);
        u16* dst = APack + (size_t)(step + 1) * 262144
                 + ((size_t)((mp * 2 + mm) * 128 + ct32)) * 512 + lane * 8;
        st_dev((u64*)dst, lo);
        st_dev((u64*)dst + 1, hi);
      }
      asm volatile("s_waitcnt vmcnt(0)" ::: "memory");
      __syncthreads();
      if (tix == 0)
        __hip_atomic_store(tagB, tag, __ATOMIC_RELAXED, SCOPE_AGT);
      // deferred output stores: drain overlaps next-step waits
      #pragma unroll
      for (int ri = 0; ri < 2; ++ri) {
        const int row = mp * 32 + eM * 16 + lq * 4 + eRh * 2 + ri;
        #pragma unroll
        for (int s = 0; s < 4; ++s)
          __builtin_nontemporal_store(
              sg[ri], &out[((size_t)(s * 64 + step + 1) * 64 + row) * 4096 + nc]);
      }
    }
  }
}

// ---------------- launch ----------------
extern "C" void kernel_launch(void* const* d_in, const int* in_sizes, int n_in,
                              void* d_out, int out_size, void* d_ws, size_t ws_size,
                              hipStream_t stream) {
  const float* A0 = (const float*)d_in[0];
  const float* tarr = (const float*)d_in[1];
  const float* W1f = (const float*)d_in[2];
  const float* b1f = (const float*)d_in[3];
  const float* W2f = (const float*)d_in[4];
  const float* b2f = (const float*)d_in[5];
  const float* W1g = (const float*)d_in[6];
  const float* b1g = (const float*)d_in[7];
  const float* W2g = (const float*)d_in[8];
  const float* b2g = (const float*)d_in[9];
  float* outp = (float*)d_out;
  char* ws = (char*)d_ws;
  const size_t MB = 1024 * 1024;
  u16* W1P   = (u16*)(ws + 0 * MB);        // 16 MB frag-packed
  u16* W2P   = (u16*)(ws + 16 * MB);       // 16 MB
  u16* APack = (u16*)(ws + 32 * MB);       // 64 step-buffers x 512 KB = 32 MB
  u16* HPack = (u16*)(ws + 64 * MB);       // 63 step-buffers x 256 KB ~ 16 MB
  u32* ctr   = (u32*)(ws + 80 * MB);       // 512 padded tag lines (64 KB)

  s1_frag<<<dim3(8192), 256, 0, stream>>>(W1f, W1g, W2f, W2g, W1P, W2P);
  s2_init<<<dim3(1024), 256, 0, stream>>>(A0, APack, ctr, outp);

  void* kargs[] = {
    (void*)&A0, (void*)&tarr,
    (void*)&W1P, (void*)&W2P,
    (void*)&b1f, (void*)&b1g, (void*)&W1f, (void*)&W1g,
    (void*)&b2f, (void*)&b2g,
    (void*)&APack, (void*)&HPack, (void*)&ctr, (void*)&outp
  };
  hipLaunchCooperativeKernel((const void*)sde_fused, dim3(256), dim3(512),
                             kargs, 150016, stream);
}

// Round 15
// 662.353 us; speedup vs baseline: 1.4052x; 1.0937x over previous
//
#include <hip/hip_runtime.h>
#include <cstdint>

using u16 = unsigned short;
using u32 = uint32_t;
using u64 = unsigned long long;

typedef __bf16 bf16x8 __attribute__((ext_vector_type(8)));
typedef float  f32x4  __attribute__((ext_vector_type(4)));
typedef u32    uvec4  __attribute__((ext_vector_type(4)));

typedef const __attribute__((address_space(1))) void GV;
typedef __attribute__((address_space(3))) void LV;

#define MFMA(a, b, c) __builtin_amdgcn_mfma_f32_16x16x32_bf16((a), (b), (c), 0, 0, 0)
#define SCOPE_AGT __HIP_MEMORY_SCOPE_AGENT

static __device__ __forceinline__ void gl_lds16(const u16* g, u16* l) {
  __builtin_amdgcn_global_load_lds((GV*)g, (LV*)l, 16, 0, 0);
}
static __device__ __forceinline__ void st_dev(u64* p, u64 v) {
  __hip_atomic_store(p, v, __ATOMIC_RELAXED, SCOPE_AGT);
}
// per-wave wait: poll 32 producer tag lines (padded 128B) until all >= tag
static __device__ __forceinline__ void wait_tags(const u32* ctr, int base, u32 tag) {
  const int lane = threadIdx.x & 63;
  const u32* p = ctr + (size_t)(base + (lane & 31)) * 32;
  u32 v = __hip_atomic_load(p, __ATOMIC_RELAXED, SCOPE_AGT);
  while (!__all(v >= tag)) {
    __builtin_amdgcn_s_sleep(1);
    v = __hip_atomic_load(p, __ATOMIC_RELAXED, SCOPE_AGT);
  }
  asm volatile("" ::: "memory");   // keep data loads below the wait
}

// ---------------- fast transcendentals (v_exp/v_log/v_rcp based) ----------------
static __device__ __forceinline__ float tanh_fast(float x) {
  return 1.0f - 2.0f * __builtin_amdgcn_rcpf(1.0f + __expf(2.0f * x));
}
static __device__ __forceinline__ float softplus_fast(float x) {
  return fmaxf(x, 0.0f) + __logf(1.0f + __expf(-fabsf(x)));
}
static __device__ __forceinline__ float sigmoid_fast(float x) {
  return __builtin_amdgcn_rcpf(1.0f + __expf(-x));
}

// ---------------- numeric helpers ----------------
static __device__ __forceinline__ u16 f2bf(float x) {
  u32 u = __float_as_uint(x);
  u32 r = (u + 0x7FFFu + ((u >> 16) & 1u)) >> 16;   // RNE
  return (u16)r;
}

static __device__ __forceinline__ u32 rotl32(u32 v, int s) {
  return (v << s) | (v >> (32 - s));
}

// JAX threefry2x32 (20 rounds)
static __device__ __forceinline__ void threefry2x32(u32 k0, u32 k1, u32 x0, u32 x1,
                                                    u32& o0, u32& o1) {
  u32 k2 = k0 ^ k1 ^ 0x1BD11BDAu;
  x0 += k0; x1 += k1;
  x0 += x1; x1 = rotl32(x1, 13); x1 ^= x0;
  x0 += x1; x1 = rotl32(x1, 15); x1 ^= x0;
  x0 += x1; x1 = rotl32(x1, 26); x1 ^= x0;
  x0 += x1; x1 = rotl32(x1, 6);  x1 ^= x0;
  x0 += k1; x1 += k2 + 1u;
  x0 += x1; x1 = rotl32(x1, 17); x1 ^= x0;
  x0 += x1; x1 = rotl32(x1, 29); x1 ^= x0;
  x0 += x1; x1 = rotl32(x1, 16); x1 ^= x0;
  x0 += x1; x1 = rotl32(x1, 24); x1 ^= x0;
  x0 += k2; x1 += k0 + 2u;
  x0 += x1; x1 = rotl32(x1, 13); x1 ^= x0;
  x0 += x1; x1 = rotl32(x1, 15); x1 ^= x0;
  x0 += x1; x1 = rotl32(x1, 26); x1 ^= x0;
  x0 += x1; x1 = rotl32(x1, 6);  x1 ^= x0;
  x0 += k0; x1 += k1 + 3u;
  x0 += x1; x1 = rotl32(x1, 17); x1 ^= x0;
  x0 += x1; x1 = rotl32(x1, 29); x1 ^= x0;
  x0 += x1; x1 = rotl32(x1, 16); x1 ^= x0;
  x0 += x1; x1 = rotl32(x1, 24); x1 ^= x0;
  x0 += k1; x1 += k2 + 4u;
  x0 += x1; x1 = rotl32(x1, 13); x1 ^= x0;
  x0 += x1; x1 = rotl32(x1, 15); x1 ^= x0;
  x0 += x1; x1 = rotl32(x1, 26); x1 ^= x0;
  x0 += x1; x1 = rotl32(x1, 6);  x1 ^= x0;
  x0 += k2; x1 += k0 + 5u;
  o0 = x0; o1 = x1;
}

// bits -> N(0,1) exactly like jax.random.normal(f32)
static __device__ __forceinline__ float bits_to_normal(u32 bits) {
  const float lo = __uint_as_float(0xBF7FFFFFu);
  float f = __uint_as_float((bits >> 9) | 0x3F800000u) - 1.0f;
  float x = fmaxf(lo, f * 2.0f + lo);
  float w = -logf((1.0f - x) * (1.0f + x));
  float p;
  if (w < 5.0f) {
    w -= 2.5f;
    p = 2.81022636e-08f;
    p = fmaf(p, w, 3.43273939e-07f);
    p = fmaf(p, w, -3.5233877e-06f);
    p = fmaf(p, w, -4.39150654e-06f);
    p = fmaf(p, w, 0.00021858087f);
    p = fmaf(p, w, -0.00125372503f);
    p = fmaf(p, w, -0.00417768164f);
    p = fmaf(p, w, 0.246640727f);
    p = fmaf(p, w, 1.50140941f);
  } else {
    w = sqrtf(w) - 3.0f;
    p = -0.000200214257f;
    p = fmaf(p, w, 0.000100950558f);
    p = fmaf(p, w, 0.00134934322f);
    p = fmaf(p, w, -0.00367342844f);
    p = fmaf(p, w, 0.00573950773f);
    p = fmaf(p, w, -0.0076224613f);
    p = fmaf(p, w, 0.00943887047f);
    p = fmaf(p, w, 1.00167406f);
    p = fmaf(p, w, 2.83297682f);
  }
  return 1.41421356f * p * x;
}

// ---------------- S1: fragment-pack weights from f32 (r7 layout) ----------------
__global__ __launch_bounds__(256) void s1_frag(
    const float* __restrict__ W1f, const float* __restrict__ W1g,
    const float* __restrict__ W2f, const float* __restrict__ W2g,
    u16* __restrict__ W1P, u16* __restrict__ W2P) {
  const int gid = blockIdx.x * 256 + threadIdx.x;
  const int f = gid >> 6, l = gid & 63;
  const int lr = l & 15, kg = l >> 4;
  u32 wbuf[4];
  if (f < 16384) {                       // W1P: (net*64+ct)*128 + q
    const int net = f >> 13, r = f & 8191, ct = r >> 7, q = r & 127;
    const float* __restrict__ src = net ? W1g : W1f;
    const int k = q * 32 + kg * 8, c = ct * 16 + lr;
    #pragma unroll
    for (int p = 0; p < 4; ++p) {
      u16 e0 = f2bf(src[(size_t)(k + 2 * p) * 1024 + c]);
      u16 e1 = f2bf(src[(size_t)(k + 2 * p + 1) * 1024 + c]);
      wbuf[p] = (u32)e0 | ((u32)e1 << 16);
    }
    *(uvec4*)(W1P + (size_t)f * 512 + l * 8) = *(uvec4*)wbuf;
  } else {                               // W2P: (net*256+ct16)*32 + q
    const int f2 = f - 16384;
    const int net = f2 >> 13, r = f2 & 8191, ct = r >> 5, q = r & 31;
    const float* __restrict__ src = net ? W2g : W2f;
    const int k = q * 32 + kg * 8, c = ct * 16 + lr;
    #pragma unroll
    for (int p = 0; p < 4; ++p) {
      u16 e0 = f2bf(src[(size_t)(k + 2 * p) * 4096 + c]);
      u16 e1 = f2bf(src[(size_t)(k + 2 * p + 1) * 4096 + c]);
      wbuf[p] = (u32)e0 | ((u32)e1 << 16);
    }
    *(uvec4*)(W2P + (size_t)f2 * 512 + l * 8) = *(uvec4*)wbuf;
  }
}

// ---------------- S2: t=0 output, APack[0] init, tag lines zero ----------------
__global__ __launch_bounds__(256) void s2_init(
    const float* __restrict__ A0, u16* __restrict__ APack,
    u32* __restrict__ ctr, float* __restrict__ out) {
  const int gid = blockIdx.x * 256 + threadIdx.x;   // 262144
  const int n = gid & 4095, b = gid >> 12;
  const float a0 = A0[gid];
  const float sig = (n % 65 == 0) ? 0.0f : 1.0f / (1.0f + expf(-a0));
  #pragma unroll
  for (int s = 0; s < 4; ++s)
    out[((size_t)(s * 64) * 64 + b) * 4096 + n] = sig;
  if (gid < 32768) {                     // APack[0]: [m 4][q 128] frags
    const int fr = gid >> 6, l = gid & 63;
    const int m = fr >> 7, q = fr & 127;
    const int row = m * 16 + (l & 15);
    const int k = q * 32 + (l >> 4) * 8;
    u32 wbuf[4];
    #pragma unroll
    for (int p = 0; p < 4; ++p) {
      u16 e0 = f2bf(A0[(size_t)row * 4096 + k + 2 * p]);
      u16 e1 = f2bf(A0[(size_t)row * 4096 + k + 2 * p + 1]);
      wbuf[p] = (u32)e0 | ((u32)e1 << 16);
    }
    *(uvec4*)(APack + (size_t)fr * 512 + l * 8) = *(uvec4*)wbuf;
  }
  if (gid < 16640) ctr[gid] = 0;         // tag lines; re-zero every launch (replays)
}

// ---------------- dW pregen (r7-proven): all 63 steps ----------------
__global__ __launch_bounds__(256) void dw_gen(
    const float* __restrict__ tarr, float* __restrict__ dst_base) {
  const int bid = blockIdx.x, tix = threadIdx.x;
  const int step = bid >> 5, sub = bid & 31;
  u32 k0, k1;
  threefry2x32(0u, 42u, 0u, (u32)step, k0, k1);
  const float sdt = sqrtf(tarr[1] - tarr[0]);
  float* dst = dst_base + (size_t)step * 262144;
  #pragma unroll
  for (int j = 0; j < 32; ++j) {
    u32 e = (u32)(sub * 8192 + j * 256 + tix);
    u32 y0, y1;
    threefry2x32(k0, k1, 0u, e, y0, y1);
    dst[e] = bits_to_normal(y0 ^ y1) * sdt;
  }
}

// ---------------- fused 63-step SDE: W1 regs, W2 LDS, tag-array direct sync ----------------
// ctr lines (128B): tagA = bid (phase A done), tagB = 256+bid (phase B done)
__global__ __launch_bounds__(512, 2) void sde_fused(
    const float* __restrict__ A0, const float* __restrict__ tarr,
    const u16* __restrict__ W1P, const u16* __restrict__ W2P,
    const float* __restrict__ b1f, const float* __restrict__ b1g,
    const float* __restrict__ W1fv, const float* __restrict__ W1gv,
    const float* __restrict__ b2f, const float* __restrict__ b2g,
    u16* __restrict__ APack, u16* __restrict__ HPack,
    u32* __restrict__ ctr, const float* __restrict__ dwall,
    float* __restrict__ out) {
  extern __shared__ __align__(16) char smraw[];
  u16* w2l = (u16*)smraw;                                    // 128 KB W2 slice
  char* exraw = smraw + 131072;
  f32x4 (*paex)[64]     = (f32x4 (*)[64])exraw;              // 8 KB
  u16 (*patile)[16][16] = (u16 (*)[16][16])(exraw + 8192);   // 1 KB
  f32x4 (*pbex)[64][2]  = (f32x4 (*)[64][2])exraw;           // 16 KB (aliases paex)
  u16 (*pbtile)[16][32] = (u16 (*)[16][32])(exraw + 16384);  // 2 KB
  uint2* dwk = (uint2*)(exraw + 18432);                      // 504 B
  float* tarrl = (float*)(exraw + 18944);                    // 256 B

  const int bid = blockIdx.x, tix = threadIdx.x;
  const int wid = tix >> 6, lane = tix & 63;
  const int lr = lane & 15, lq = lane >> 4;
  const int mp = bid >> 7;
  const int ctF = bid & 127;
  const int netA = ctF >> 6, ctA = ctF & 63;
  const int mA = wid & 1, ksA = wid >> 1;
  const int mGA = mp * 2 + mA;
  const int ct32 = bid & 127;
  const int ksB = wid >> 2, netB = (wid >> 1) & 1, mB = wid & 1;
  const int mGB = mp * 2 + mB;
  const int eM = wid & 1, eCf = (wid >> 1) & 1, eRh = wid >> 2;
  const int nc = ct32 * 32 + eCf * 16 + lr;

  // tag plumbing
  u32* tagA = ctr + (size_t)bid * 32;
  u32* tagB = ctr + (size_t)(256 + bid) * 32;
  const int waitAbase = 256 + mp * 128 + ksA * 32;        // phase A needs these B-producers
  const int waitBbase = mp * 128 + netB * 64 + ksB * 32;  // phase B needs these A-producers

  // ---- prologue: W2 slice -> LDS (f = net*64 + c*32 + ks*16 + d)
  #pragma unroll
  for (int i = 0; i < 16; ++i) {
    const int f = wid * 16 + i;
    const int nf = f >> 6, cf = (f >> 5) & 1, ksf = (f >> 4) & 1, df = f & 15;
    const u16* src = W2P
        + ((size_t)((nf * 256 + ct32 * 2 + cf) * 32 + ksf * 16 + df)) * 512 + lane * 8;
    gl_lds16(src, w2l + (size_t)f * 512);
  }
  if (tix < 63) {                        // dW step keys (fallback path)
    u32 y0, y1;
    threefry2x32(0u, 42u, 0u, (u32)tix, y0, y1);
    dwk[tix] = make_uint2(y0, y1);
  }
  if (tix >= 64 && tix < 127) tarrl[tix - 64] = tarr[tix - 64];
  // persistent W1 column slice: 32 frags
  bf16x8 wv[32];
  {
    const u16* pw = W1P + ((size_t)((netA * 64 + ctA) * 128 + ksA * 32)) * 512 + lane * 8;
    #pragma unroll
    for (int d = 0; d < 32; ++d) wv[d] = *(const bf16x8*)(pw + (size_t)d * 512);
  }
  // A-state in registers + hoisted epilogue constants
  float Ast[2];
  #pragma unroll
  for (int ri = 0; ri < 2; ++ri) {
    const int row = mp * 32 + eM * 16 + lq * 4 + eRh * 2 + ri;
    Ast[ri] = A0[(size_t)row * 4096 + nc];
  }
  const int nclA = ctA * 16 + lr;
  const float bAc = (netA ? b1g : b1f)[nclA];
  const float wAc = ((netA ? W1gv : W1fv) + (size_t)4096 * 1024)[nclA];
  const float bfv = b2f[nc], bgv = b2g[nc];
  const bool diag0 = (nc % 65 == 0);
  const int e0dw = (mp * 32 + eM * 16 + lq * 4 + eRh * 2) * 4096 + nc;
  asm volatile("s_waitcnt vmcnt(0)" ::: "memory");
  __syncthreads();

  const float dt = tarr[1] - tarr[0];
  const float sdt = sqrtf(dt);

  for (int step = 0; step < 63; ++step) {
    const u32 tag = (u32)step + 1u;
    // ===== phase A: HPack[step] = frag(tanh(A @ W1 + b1 + t*w1last)) =====
    {
      wait_tags(ctr, waitAbase, (u32)step);   // APack[step] producers done (trivial at 0)
      const u16* pa = APack + (size_t)step * 262144
                    + ((size_t)(mGA * 128 + ksA * 32)) * 512 + lane * 8;
      bf16x8 av[16];
      #pragma unroll
      for (int d = 0; d < 16; ++d) av[d] = *(const bf16x8*)(pa + (size_t)d * 512);
      f32x4 acc0 = {0.f, 0.f, 0.f, 0.f}, acc1 = acc0;
      #pragma unroll
      for (int j = 0; j < 32; ++j) {
        const int s = j & 15;
        if (j & 1) acc1 = MFMA(av[s], wv[j], acc1);
        else       acc0 = MFMA(av[s], wv[j], acc0);
        if (j + 16 < 32) av[s] = *(const bf16x8*)(pa + (size_t)(j + 16) * 512);
      }
      paex[wid][lane] = acc0 + acc1;
      __syncthreads();
      {
        const int gM = wid & 1, gR = wid >> 1;
        const f32x4 s0 = paex[gM][lane];
        const f32x4 s1 = paex[2 + gM][lane];
        const f32x4 s2 = paex[4 + gM][lane];
        const f32x4 s3 = paex[6 + gM][lane];
        const float ch = s0[gR] + s1[gR] + s2[gR] + s3[gR];
        const float cc = bAc + tarrl[step] * wAc;
        patile[gM][lq * 4 + gR][lr] = f2bf(tanh_fast(ch + cc));
      }
      __syncthreads();
      if (wid < 2 && lane < 32) {
        const int mm = wid;
        const int row = lane & 15, kp = lane >> 4;
        const u16* src = &patile[mm][row][kp * 8];
        const u64 lo = *(const u64*)src;
        const u64 hi = *(const u64*)(src + 4);
        const int k8 = (ctA & 1) * 2 + kp;
        u16* dst = HPack + (size_t)step * 131072
                 + ((size_t)((netA * 4 + mp * 2 + mm) * 32 + (ctA >> 1))) * 512
                 + (k8 * 16 + row) * 8;
        st_dev((u64*)dst, lo);
        st_dev((u64*)dst + 1, hi);
      }
      asm volatile("s_waitcnt vmcnt(0)" ::: "memory");
      __syncthreads();
      if (tix == 0)
        __hip_atomic_store(tagA, tag, __ATOMIC_RELAXED, SCOPE_AGT);
    }

    // ===== phase B: C = H @ W2 (f,g) -> SDE update =====
    {
      float dwv0 = 0.f, dwv1 = 0.f;
      if (dwall) {                        // prefetch: independent of producers
        dwv0 = dwall[(size_t)step * 262144 + e0dw];
        dwv1 = dwall[(size_t)step * 262144 + e0dw + 4096];
      }
      wait_tags(ctr, waitBbase, tag);    // HPack[step] producers done
      const u16* ph = HPack + (size_t)step * 131072
                    + ((size_t)((netB * 4 + mGB) * 32 + ksB * 16)) * 512 + lane * 8;
      bf16x8 hv[16];
      #pragma unroll
      for (int d = 0; d < 16; ++d) hv[d] = *(const bf16x8*)(ph + (size_t)d * 512);
      const u16* wl0 = w2l + (size_t)(netB * 64 + ksB * 16) * 512 + lane * 8;
      const u16* wl1 = wl0 + (size_t)32 * 512;
      f32x4 a0 = {0.f, 0.f, 0.f, 0.f}, a1 = a0;
      #pragma unroll
      for (int j = 0; j < 16; ++j) {
        const bf16x8 w0 = *(const bf16x8*)(wl0 + (size_t)j * 512);
        const bf16x8 w1 = *(const bf16x8*)(wl1 + (size_t)j * 512);
        a0 = MFMA(hv[j], w0, a0);
        a1 = MFMA(hv[j], w1, a1);
      }
      pbex[wid][lane][0] = a0;
      pbex[wid][lane][1] = a1;
      __syncthreads();
      float anv[2];
      {
        const f32x4 CF = pbex[eM][lane][eCf] + pbex[4 + eM][lane][eCf];
        const f32x4 CG = pbex[2 + eM][lane][eCf] + pbex[6 + eM][lane][eCf];
        uint2 key;
        if (!dwall) key = dwk[step];
        #pragma unroll
        for (int ri = 0; ri < 2; ++ri) {
          const int r = eRh * 2 + ri;
          float dwv = ri ? dwv1 : dwv0;
          if (!dwall) {
            u32 y0, y1;
            threefry2x32(key.x, key.y, 0u, (u32)(e0dw + ri * 4096), y0, y1);
            dwv = bits_to_normal(y0 ^ y1) * sdt;
          }
          const float drift = CF[r] + bfv;
          const float graw = CG[r] + bgv;
          const float diff = softplus_fast(graw);
          const float an = Ast[ri] + drift * dt + diff * dwv;
          Ast[ri] = an;
          anv[ri] = an;
          pbtile[eM][lq * 4 + r][eCf * 16 + lr] = f2bf(an);
        }
      }
      __syncthreads();
      if (wid < 2) {
        const int mm = wid;
        const int row = lane & 15, kq = lane >> 4;
        const u16* src = &pbtile[mm][row][kq * 8];
        const u64 lo = *(const u64*)src;
        const u64 hi = *(const u64*)(src + 4);
        u16* dst = APack + (size_t)(step + 1) * 262144
                 + ((size_t)((mp * 2 + mm) * 128 + ct32)) * 512 + lane * 8;
        st_dev((u64*)dst, lo);
        st_dev((u64*)dst + 1, hi);
      }
      asm volatile("s_waitcnt vmcnt(0)" ::: "memory");
      __syncthreads();
      if (tix == 0)
        __hip_atomic_store(tagB, tag, __ATOMIC_RELAXED, SCOPE_AGT);
      // sigmoid + deferred output stores: off the handoff critical path
      #pragma unroll
      for (int ri = 0; ri < 2; ++ri) {
        const float sg = diag0 ? 0.0f : sigmoid_fast(anv[ri]);
        const int row = mp * 32 + eM * 16 + lq * 4 + eRh * 2 + ri;
        #pragma unroll
        for (int s = 0; s < 4; ++s)
          __builtin_nontemporal_store(
              sg, &out[((size_t)(s * 64 + step + 1) * 64 + row) * 4096 + nc]);
      }
    }
  }
}

// ---------------- launch ----------------
extern "C" void kernel_launch(void* const* d_in, const int* in_sizes, int n_in,
                              void* d_out, int out_size, void* d_ws, size_t ws_size,
                              hipStream_t stream) {
  const float* A0 = (const float*)d_in[0];
  const float* tarr = (const float*)d_in[1];
  const float* W1f = (const float*)d_in[2];
  const float* b1f = (const float*)d_in[3];
  const float* W2f = (const float*)d_in[4];
  const float* b2f = (const float*)d_in[5];
  const float* W1g = (const float*)d_in[6];
  const float* b1g = (const float*)d_in[7];
  const float* W2g = (const float*)d_in[8];
  const float* b2g = (const float*)d_in[9];
  float* outp = (float*)d_out;
  char* ws = (char*)d_ws;
  const size_t MB = 1024 * 1024;
  u16* W1P   = (u16*)(ws + 0 * MB);        // 16 MB frag-packed
  u16* W2P   = (u16*)(ws + 16 * MB);       // 16 MB
  u16* APack = (u16*)(ws + 32 * MB);       // 64 step-buffers x 512 KB = 32 MB
  u16* HPack = (u16*)(ws + 64 * MB);       // 63 step-buffers x 256 KB ~ 16 MB
  u32* ctr   = (u32*)(ws + 80 * MB);       // 512 padded tag lines (64 KB)
  float* dwall = (ws_size >= (size_t)145 * MB) ? (float*)(ws + 81 * MB) : nullptr;  // 63 MB

  s1_frag<<<dim3(8192), 256, 0, stream>>>(W1f, W1g, W2f, W2g, W1P, W2P);
  s2_init<<<dim3(1024), 256, 0, stream>>>(A0, APack, ctr, outp);
  if (dwall) dw_gen<<<dim3(63 * 32), 256, 0, stream>>>(tarr, dwall);

  void* kargs[] = {
    (void*)&A0, (void*)&tarr,
    (void*)&W1P, (void*)&W2P,
    (void*)&b1f, (void*)&b1g, (void*)&W1f, (void*)&W1g,
    (void*)&b2f, (void*)&b2g,
    (void*)&APack, (void*)&HPack, (void*)&ctr, (void*)&dwall, (void*)&outp
  };
  hipLaunchCooperativeKernel((const void*)sde_fused, dim3(256), dim3(512),
                             kargs, 150016, stream);
}